// Round 3
// baseline (322.095 us; speedup 1.0000x reference)
//
#include <hip/hip_runtime.h>
#include <math.h>

#define N_NODES 50000
#define SLICE_SZ 6250          // N_NODES / 8 XCDs

// ---------------- degree histogram ----------------
__global__ void count_kernel(const int* __restrict__ dst, int E, int* __restrict__ counts) {
    int i = blockIdx.x * blockDim.x + threadIdx.x;
    if (i < E) atomicAdd(&counts[dst[i]], 1);
}

// ---------------- block-level exclusive scan ----------------
__global__ void scan_block_kernel(const int* __restrict__ in, int n,
                                  int* __restrict__ outEx, int* __restrict__ blocksum) {
    __shared__ int s[256];
    int t = threadIdx.x, i = blockIdx.x * 256 + t;
    int v = (i < n) ? in[i] : 0;
    s[t] = v;
    __syncthreads();
    for (int off = 1; off < 256; off <<= 1) {
        int x = (t >= off) ? s[t - off] : 0;
        __syncthreads();
        s[t] += x;
        __syncthreads();
    }
    if (i < n) outEx[i] = s[t] - v;
    if (t == 255 && blocksum) blocksum[blockIdx.x] = s[255];
}

__global__ void finalize_kernel(const int* __restrict__ counts, const int* __restrict__ blocksum,
                                int n, int E, int* __restrict__ row_ptr,
                                int* __restrict__ cursor, float* __restrict__ dinv) {
    int i = blockIdx.x * blockDim.x + threadIdx.x;
    if (i < n) {
        int rp = row_ptr[i] + blocksum[i >> 8];
        row_ptr[i] = rp;
        cursor[i]  = rp;
        dinv[i] = rsqrtf((float)(counts[i] + 1));   // +1 self-loop
        if (i == 0) row_ptr[n] = E;
    }
}

// ---------------- XCD-sliced CSR fill ----------------
// Block commits only edges whose dst lies in its XCD's node slice, so each
// 64B line of the edges array is assembled inside ONE per-XCD L2 (full-line
// eviction instead of 8 partial-line evictions -> ~8x less HBM write traffic).
__global__ void fill_sliced_kernel(const int* __restrict__ src, const int* __restrict__ dst,
                                   int E, int* __restrict__ cursor,
                                   const float* __restrict__ dinv, int2* __restrict__ edges) {
    const int slice = blockIdx.x & 7;          // XCD heuristic (round-robin)
    const int chunk = blockIdx.x >> 3;         // 256 edge chunks
    const int CS = (E + 255) / 256;
    int lo = chunk * CS;
    int hi = min(E, lo + CS);
    for (int i = lo + threadIdx.x; i < hi; i += 256) {
        int d = dst[i];
        if (d / SLICE_SZ == slice) {
            int s = src[i];
            int p = atomicAdd(&cursor[d], 1);
            edges[p] = make_int2(s, __float_as_int(dinv[s] * dinv[d]));
        }
    }
}

// ---------------- fp32 GEMM: C[n,DOUT] = A[n,DIN] @ W[DIN,DOUT] ----------------
template<int DIN, int DOUT, int BM, int KC>
__global__ __launch_bounds__(256) void gemm_kernel(const float* __restrict__ A,
                                                   const float* __restrict__ W,
                                                   float* __restrict__ C, int n) {
    constexpr int NCG = DOUT / 4;
    constexpr int NRG = BM / 4;
    static_assert(NCG * NRG == 256, "thread mapping");
    constexpr int KG = KC / 4;
    constexpr int RSTEP = 256 / KG;
    __shared__ __align__(16) float ws[DIN * DOUT];
    __shared__ __align__(16) float xs[KC][BM + 4];
    const int t = threadIdx.x;
    for (int i = 4 * t; i < DIN * DOUT; i += 1024)
        *(float4*)&ws[i] = *(const float4*)&W[i];
    const int rowbase = blockIdx.x * BM;
    const int r0 = (t / NCG) * 4;
    const int c0 = (t % NCG) * 4;
    const int lk = (t % KG) * 4;
    const int lr = t / KG;
    float acc[4][4] = {};
    for (int kc = 0; kc < DIN; kc += KC) {
        __syncthreads();
        #pragma unroll
        for (int r = lr; r < BM; r += RSTEP) {
            int row = rowbase + r;
            if (row >= n) row = n - 1;
            float4 v = *(const float4*)&A[(size_t)row * DIN + kc + lk];
            xs[lk + 0][r] = v.x; xs[lk + 1][r] = v.y;
            xs[lk + 2][r] = v.z; xs[lk + 3][r] = v.w;
        }
        __syncthreads();
        #pragma unroll
        for (int k = 0; k < KC; ++k) {
            float ar[4], wr[4];
            *(float4*)ar = *(const float4*)&xs[k][r0];
            *(float4*)wr = *(const float4*)&ws[(kc + k) * DOUT + c0];
            #pragma unroll
            for (int i = 0; i < 4; ++i)
                #pragma unroll
                for (int j = 0; j < 4; ++j)
                    acc[i][j] += ar[i] * wr[j];
        }
    }
    #pragma unroll
    for (int i = 0; i < 4; ++i) {
        int row = rowbase + r0 + i;
        if (row < n) {
            float4 v = make_float4(acc[i][0], acc[i][1], acc[i][2], acc[i][3]);
            *(float4*)&C[(size_t)row * DOUT + c0] = v;
        }
    }
}

// ---------------- layer-1 gather, feature-quarter XCD-affine ----------------
// XCD pair (blockIdx&7)>>1 == fq gathers only features [fq*16, fq*16+16):
// per-XCD XW working set = 3.2MB < 4MB L2, so the random gather hits L2.
// Wave layout: lanes 0-15 = features, lane>>4 = 4 parallel edge ways.
__global__ __launch_bounds__(256) void gather64_sliced_kernel(
        const float* __restrict__ XW, const int* __restrict__ row_ptr,
        const int2* __restrict__ edges, const float* __restrict__ dinv,
        const float* __restrict__ b1, float* __restrict__ h1, int n) {
    const int x = blockIdx.x & 7;                       // XCD heuristic
    const int fq = x >> 1;                              // feature quarter
    const int chunk = (blockIdx.x >> 3) * 2 + (x & 1);  // node chunk (64 nodes)
    const int w = threadIdx.x >> 6;
    const int lane = threadIdx.x & 63;
    const int f = lane & 15, way = lane >> 4;
    const int fcol = fq * 16 + f;
    const float bias = b1[fcol];
    #pragma unroll 1
    for (int it = 0; it < 16; ++it) {
        int node = chunk * 64 + w * 16 + it;
        if (node >= n) break;
        int start = row_ptr[node], end = row_ptr[node + 1];
        float acc = 0.f;
        if (way == 0) {
            float dv = dinv[node];
            acc = dv * dv * XW[(size_t)node * 64 + fcol];
        }
        int e = start + way;
        for (; e + 4 < end; e += 8) {                   // 8 edges in flight per wave
            int2 p0 = edges[e], p1 = edges[e + 4];
            float v0 = XW[(size_t)p0.x * 64 + fcol];
            float v1 = XW[(size_t)p1.x * 64 + fcol];
            acc += __int_as_float(p0.y) * v0;
            acc += __int_as_float(p1.y) * v1;
        }
        for (; e < end; e += 4) {
            int2 p = edges[e];
            acc += __int_as_float(p.y) * XW[(size_t)p.x * 64 + fcol];
        }
        acc += __shfl_xor(acc, 16, 64);                 // reduce 4 ways
        acc += __shfl_xor(acc, 32, 64);
        if (way == 0)
            h1[(size_t)node * 64 + fcol] = fmaxf(acc + bias, 0.f);
    }
}

// ---------------- layer-2 gather (D=32) + attention epilogue ----------------
__global__ __launch_bounds__(256) void gather32_final_kernel(
        const float* __restrict__ XW, const int* __restrict__ row_ptr,
        const int2* __restrict__ edges, const float* __restrict__ dinv,
        const float* __restrict__ bias, const float* __restrict__ aw,
        const float* __restrict__ ab, float* __restrict__ out, int n) {
    int gid = blockIdx.x * blockDim.x + threadIdx.x;
    int node = gid >> 6;
    int lane = threadIdx.x & 63;
    int f = lane & 31, half = lane >> 5;
    if (node >= n) return;
    float acc = 0.f;
    if (half == 0) {
        float dv = dinv[node];
        acc = dv * dv * XW[(size_t)node * 32 + f];
    }
    int end = row_ptr[node + 1];
    int e = row_ptr[node] + half;
    for (; e + 6 < end; e += 8) {
        int2 p0 = edges[e+0], p1 = edges[e+2], p2 = edges[e+4], p3 = edges[e+6];
        float v0 = XW[(size_t)p0.x * 32 + f], v1 = XW[(size_t)p1.x * 32 + f];
        float v2 = XW[(size_t)p2.x * 32 + f], v3 = XW[(size_t)p3.x * 32 + f];
        acc += __int_as_float(p0.y) * v0; acc += __int_as_float(p1.y) * v1;
        acc += __int_as_float(p2.y) * v2; acc += __int_as_float(p3.y) * v3;
    }
    for (; e < end; e += 2) {
        int2 p = edges[e];
        acc += __int_as_float(p.y) * XW[(size_t)p.x * 32 + f];
    }
    acc += __shfl_xor(acc, 32, 64);
    float h = fmaxf(acc + bias[f], 0.f);
    float sca = h * aw[f];
    #pragma unroll
    for (int m = 16; m >= 1; m >>= 1) sca += __shfl_xor(sca, m, 64);
    float attn = 1.f / (1.f + __expf(-(sca + ab[0])));
    if (half == 0) out[(size_t)node * 32 + f] = h * attn;
}

extern "C" void kernel_launch(void* const* d_in, const int* in_sizes, int n_in,
                              void* d_out, int out_size, void* d_ws, size_t ws_size,
                              hipStream_t stream) {
    const float* x  = (const float*)d_in[0];
    const int*   ei = (const int*)d_in[1];
    const float* W1 = (const float*)d_in[2];
    const float* b1 = (const float*)d_in[3];
    const float* W2 = (const float*)d_in[4];
    const float* b2 = (const float*)d_in[5];
    const float* aw = (const float*)d_in[6];
    const float* ab = (const float*)d_in[7];
    float* out = (float*)d_out;

    const int n = N_NODES;
    const int E = in_sizes[1] / 2;
    const int* src = ei;
    const int* dst = ei + E;

    char* w = (char*)d_ws;
    auto alloc = [&](size_t bytes) { char* p = w; w += (bytes + 255) & ~(size_t)255; return p; };
    int*   counts   = (int*)  alloc((size_t)n * 4);
    int*   row_ptr  = (int*)  alloc((size_t)(n + 1) * 4);
    int*   cursor   = (int*)  alloc((size_t)n * 4);
    int*   blocksum = (int*)  alloc(1024);
    float* dinv     = (float*)alloc((size_t)n * 4);
    int2*  edges    = (int2*) alloc((size_t)E * 8);
    float* bufA     = (float*)alloc((size_t)n * 64 * 4);   // XW1, later reused for XW2
    float* bufB     = (float*)alloc((size_t)n * 64 * 4);   // h1

    const int nb = (n + 255) / 256;

    hipMemsetAsync(counts, 0, (size_t)n * 4, stream);
    count_kernel<<<(E + 255) / 256, 256, 0, stream>>>(dst, E, counts);
    scan_block_kernel<<<nb, 256, 0, stream>>>(counts, n, row_ptr, blocksum);
    scan_block_kernel<<<1, 256, 0, stream>>>(blocksum, nb, blocksum, nullptr);
    finalize_kernel<<<nb, 256, 0, stream>>>(counts, blocksum, n, E, row_ptr, cursor, dinv);
    fill_sliced_kernel<<<256 * 8, 256, 0, stream>>>(src, dst, E, cursor, dinv, edges);

    gemm_kernel<128, 64, 64, 32><<<(n + 63) / 64, 256, 0, stream>>>(x, W1, bufA, n);
    gather64_sliced_kernel<<<392 * 8, 256, 0, stream>>>(
        bufA, row_ptr, edges, dinv, b1, bufB, n);                 // h1 in bufB
    gemm_kernel<64, 32, 128, 32><<<(n + 127) / 128, 256, 0, stream>>>(bufB, W2, bufA, n);
    gather32_final_kernel<<<((size_t)n * 64 + 255) / 256, 256, 0, stream>>>(
        bufA, row_ptr, edges, dinv, b2, aw, ab, out, n);
}

// Round 4
// 263.313 us; speedup vs baseline: 1.2232x; 1.2232x over previous
//
#include <hip/hip_runtime.h>
#include <math.h>

#define N_NODES 50000
#define SLICE_SZ 6250          // N_NODES / 8 XCDs

// ---------------- degree histogram ----------------
__global__ void count_kernel(const int* __restrict__ dst, int E, int* __restrict__ counts) {
    int i = blockIdx.x * blockDim.x + threadIdx.x;
    if (i < E) atomicAdd(&counts[dst[i]], 1);
}

// ---------------- block-level exclusive scan ----------------
__global__ void scan_block_kernel(const int* __restrict__ in, int n,
                                  int* __restrict__ outEx, int* __restrict__ blocksum) {
    __shared__ int s[256];
    int t = threadIdx.x, i = blockIdx.x * 256 + t;
    int v = (i < n) ? in[i] : 0;
    s[t] = v;
    __syncthreads();
    for (int off = 1; off < 256; off <<= 1) {
        int x = (t >= off) ? s[t - off] : 0;
        __syncthreads();
        s[t] += x;
        __syncthreads();
    }
    if (i < n) outEx[i] = s[t] - v;
    if (t == 255 && blocksum) blocksum[blockIdx.x] = s[255];
}

__global__ void finalize_kernel(const int* __restrict__ counts, const int* __restrict__ blocksum,
                                int n, int E, int* __restrict__ row_ptr,
                                int* __restrict__ cursor, float* __restrict__ dinv) {
    int i = blockIdx.x * blockDim.x + threadIdx.x;
    if (i < n) {
        int rp = row_ptr[i] + blocksum[i >> 8];
        row_ptr[i] = rp;
        cursor[i]  = rp;
        dinv[i] = rsqrtf((float)(counts[i] + 1));   // +1 self-loop
        if (i == 0) row_ptr[n] = E;
    }
}

// ---------------- XCD-sliced CSR fill ----------------
// Block commits only edges whose dst lies in its slice, so each 64B line of
// the edges array is assembled inside ONE per-XCD L2 (full-line eviction
// instead of 8 partial-line evictions -> ~8x less HBM write traffic).
__global__ void fill_sliced_kernel(const int* __restrict__ src, const int* __restrict__ dst,
                                   int E, int* __restrict__ cursor,
                                   const float* __restrict__ dinv, int2* __restrict__ edges) {
    const int slice = blockIdx.x & 7;
    const int chunk = blockIdx.x >> 3;
    const int CS = (E + 255) / 256;
    int lo = chunk * CS;
    int hi = min(E, lo + CS);
    for (int i = lo + threadIdx.x; i < hi; i += 256) {
        int d = dst[i];
        if (d / SLICE_SZ == slice) {
            int s = src[i];
            int p = atomicAdd(&cursor[d], 1);
            edges[p] = make_int2(s, __float_as_int(dinv[s] * dinv[d]));
        }
    }
}

// ---------------- fp32 GEMM: C[n,DOUT] = A[n,DIN] @ W[DIN,DOUT] ----------------
// __launch_bounds__(256,2): cap 128 VGPR -> no scratch spill (round-3 profile
// showed VGPR=256 + 6.5MB spill writes + 0.09% occupancy with full unroll).
// #pragma unroll 8 keeps the software pipeline's register footprint bounded.
template<int DIN, int DOUT, int BM, int KC>
__global__ __launch_bounds__(256, 2) void gemm_kernel(const float* __restrict__ A,
                                                      const float* __restrict__ W,
                                                      float* __restrict__ C, int n) {
    constexpr int NCG = DOUT / 4;
    constexpr int NRG = BM / 4;
    static_assert(NCG * NRG == 256, "thread mapping");
    constexpr int KG = KC / 4;
    constexpr int RSTEP = 256 / KG;
    __shared__ __align__(16) float ws[DIN * DOUT];
    __shared__ __align__(16) float xs[KC][BM + 4];
    const int t = threadIdx.x;
    for (int i = 4 * t; i < DIN * DOUT; i += 1024)
        *(float4*)&ws[i] = *(const float4*)&W[i];
    const int rowbase = blockIdx.x * BM;
    const int r0 = (t / NCG) * 4;
    const int c0 = (t % NCG) * 4;
    const int lk = (t % KG) * 4;
    const int lr = t / KG;
    float acc[4][4] = {};
    for (int kc = 0; kc < DIN; kc += KC) {
        __syncthreads();
        #pragma unroll
        for (int r = lr; r < BM; r += RSTEP) {
            int row = rowbase + r;
            if (row >= n) row = n - 1;
            float4 v = *(const float4*)&A[(size_t)row * DIN + kc + lk];
            xs[lk + 0][r] = v.x; xs[lk + 1][r] = v.y;
            xs[lk + 2][r] = v.z; xs[lk + 3][r] = v.w;
        }
        __syncthreads();
        #pragma unroll 8
        for (int k = 0; k < KC; ++k) {
            float ar[4], wr[4];
            *(float4*)ar = *(const float4*)&xs[k][r0];
            *(float4*)wr = *(const float4*)&ws[(kc + k) * DOUT + c0];
            #pragma unroll
            for (int i = 0; i < 4; ++i)
                #pragma unroll
                for (int j = 0; j < 4; ++j)
                    acc[i][j] += ar[i] * wr[j];
        }
    }
    #pragma unroll
    for (int i = 0; i < 4; ++i) {
        int row = rowbase + r0 + i;
        if (row < n) {
            float4 v = make_float4(acc[i][0], acc[i][1], acc[i][2], acc[i][3]);
            *(float4*)&C[(size_t)row * DOUT + c0] = v;
        }
    }
}

// ---------------- layer-1 gather (D=64) fused with GEMM2 (64->32) ----------------
// h[node][f] = relu(b1[f] + dinv^2*XW[node][f] + sum_e w_e*XW[col_e][f])   (f = lane)
// out[node][j] = sum_f h[f] * W2[f][j]      (in-wave via shfl; W2 in LDS)
__global__ __launch_bounds__(256) void gather64_fuse_kernel(
        const float* __restrict__ XW, const int* __restrict__ row_ptr,
        const int2* __restrict__ edges, const float* __restrict__ dinv,
        const float* __restrict__ b1, const float* __restrict__ W2,
        float* __restrict__ out, int n) {
    __shared__ __align__(16) float ws2[64 * 32];
    const int t = threadIdx.x;
    for (int i = 4 * t; i < 64 * 32; i += 1024)
        *(float4*)&ws2[i] = *(const float4*)&W2[i];
    __syncthreads();
    int gid = blockIdx.x * blockDim.x + t;
    int node = gid >> 6;
    int f = t & 63;
    if (node < n) {
        float dv = dinv[node];
        float acc = dv * dv * XW[(size_t)node * 64 + f];
        int e = row_ptr[node], end = row_ptr[node + 1];
        for (; e + 8 <= end; e += 8) {
            int2 p0 = edges[e+0], p1 = edges[e+1], p2 = edges[e+2], p3 = edges[e+3];
            int2 p4 = edges[e+4], p5 = edges[e+5], p6 = edges[e+6], p7 = edges[e+7];
            float v0 = XW[(size_t)p0.x * 64 + f], v1 = XW[(size_t)p1.x * 64 + f];
            float v2 = XW[(size_t)p2.x * 64 + f], v3 = XW[(size_t)p3.x * 64 + f];
            float v4 = XW[(size_t)p4.x * 64 + f], v5 = XW[(size_t)p5.x * 64 + f];
            float v6 = XW[(size_t)p6.x * 64 + f], v7 = XW[(size_t)p7.x * 64 + f];
            acc += __int_as_float(p0.y) * v0; acc += __int_as_float(p1.y) * v1;
            acc += __int_as_float(p2.y) * v2; acc += __int_as_float(p3.y) * v3;
            acc += __int_as_float(p4.y) * v4; acc += __int_as_float(p5.y) * v5;
            acc += __int_as_float(p6.y) * v6; acc += __int_as_float(p7.y) * v7;
        }
        if (e + 4 <= end) {
            int2 p0 = edges[e+0], p1 = edges[e+1], p2 = edges[e+2], p3 = edges[e+3];
            float v0 = XW[(size_t)p0.x * 64 + f], v1 = XW[(size_t)p1.x * 64 + f];
            float v2 = XW[(size_t)p2.x * 64 + f], v3 = XW[(size_t)p3.x * 64 + f];
            acc += __int_as_float(p0.y) * v0; acc += __int_as_float(p1.y) * v1;
            acc += __int_as_float(p2.y) * v2; acc += __int_as_float(p3.y) * v3;
            e += 4;
        }
        for (; e < end; ++e) {
            int2 p = edges[e];
            acc += __int_as_float(p.y) * XW[(size_t)p.x * 64 + f];
        }
        float h = fmaxf(acc + b1[f], 0.f);
        // fused GEMM2: y_j = sum_f h_f * W2[f][j]; halves split the f-range
        int j = f & 31, half = f >> 5;
        int fbase = half << 5;
        float y = 0.f;
        #pragma unroll
        for (int k = 0; k < 32; ++k) {
            float hf = __shfl(h, fbase + k, 64);
            y += hf * ws2[(fbase + k) * 32 + j];
        }
        y += __shfl_xor(y, 32, 64);
        if (half == 0) out[(size_t)node * 32 + j] = y;
    }
}

// ---------------- layer-2 gather (D=32) + attention epilogue ----------------
__global__ __launch_bounds__(256) void gather32_final_kernel(
        const float* __restrict__ XW, const int* __restrict__ row_ptr,
        const int2* __restrict__ edges, const float* __restrict__ dinv,
        const float* __restrict__ bias, const float* __restrict__ aw,
        const float* __restrict__ ab, float* __restrict__ out, int n) {
    int gid = blockIdx.x * blockDim.x + threadIdx.x;
    int node = gid >> 6;
    int lane = threadIdx.x & 63;
    int f = lane & 31, half = lane >> 5;
    if (node >= n) return;
    float acc = 0.f;
    if (half == 0) {
        float dv = dinv[node];
        acc = dv * dv * XW[(size_t)node * 32 + f];
    }
    int end = row_ptr[node + 1];
    int e = row_ptr[node] + half;
    for (; e + 6 < end; e += 8) {
        int2 p0 = edges[e+0], p1 = edges[e+2], p2 = edges[e+4], p3 = edges[e+6];
        float v0 = XW[(size_t)p0.x * 32 + f], v1 = XW[(size_t)p1.x * 32 + f];
        float v2 = XW[(size_t)p2.x * 32 + f], v3 = XW[(size_t)p3.x * 32 + f];
        acc += __int_as_float(p0.y) * v0; acc += __int_as_float(p1.y) * v1;
        acc += __int_as_float(p2.y) * v2; acc += __int_as_float(p3.y) * v3;
    }
    for (; e < end; e += 2) {
        int2 p = edges[e];
        acc += __int_as_float(p.y) * XW[(size_t)p.x * 32 + f];
    }
    acc += __shfl_xor(acc, 32, 64);
    float h = fmaxf(acc + bias[f], 0.f);
    float sca = h * aw[f];
    #pragma unroll
    for (int m = 16; m >= 1; m >>= 1) sca += __shfl_xor(sca, m, 64);
    float attn = 1.f / (1.f + __expf(-(sca + ab[0])));
    if (half == 0) out[(size_t)node * 32 + f] = h * attn;
}

extern "C" void kernel_launch(void* const* d_in, const int* in_sizes, int n_in,
                              void* d_out, int out_size, void* d_ws, size_t ws_size,
                              hipStream_t stream) {
    const float* x  = (const float*)d_in[0];
    const int*   ei = (const int*)d_in[1];
    const float* W1 = (const float*)d_in[2];
    const float* b1 = (const float*)d_in[3];
    const float* W2 = (const float*)d_in[4];
    const float* b2 = (const float*)d_in[5];
    const float* aw = (const float*)d_in[6];
    const float* ab = (const float*)d_in[7];
    float* out = (float*)d_out;

    const int n = N_NODES;
    const int E = in_sizes[1] / 2;
    const int* src = ei;
    const int* dst = ei + E;

    char* w = (char*)d_ws;
    auto alloc = [&](size_t bytes) { char* p = w; w += (bytes + 255) & ~(size_t)255; return p; };
    int*   counts   = (int*)  alloc((size_t)n * 4);
    int*   row_ptr  = (int*)  alloc((size_t)(n + 1) * 4);
    int*   cursor   = (int*)  alloc((size_t)n * 4);
    int*   blocksum = (int*)  alloc(1024);
    float* dinv     = (float*)alloc((size_t)n * 4);
    int2*  edges    = (int2*) alloc((size_t)E * 8);
    float* bufA     = (float*)alloc((size_t)n * 64 * 4);   // XW1
    float* bufB     = (float*)alloc((size_t)n * 32 * 4);   // XW2 (= h1 @ W2)

    const int nb = (n + 255) / 256;

    hipMemsetAsync(counts, 0, (size_t)n * 4, stream);
    count_kernel<<<(E + 255) / 256, 256, 0, stream>>>(dst, E, counts);
    scan_block_kernel<<<nb, 256, 0, stream>>>(counts, n, row_ptr, blocksum);
    scan_block_kernel<<<1, 256, 0, stream>>>(blocksum, nb, blocksum, nullptr);
    finalize_kernel<<<nb, 256, 0, stream>>>(counts, blocksum, n, E, row_ptr, cursor, dinv);
    fill_sliced_kernel<<<256 * 8, 256, 0, stream>>>(src, dst, E, cursor, dinv, edges);

    gemm_kernel<128, 64, 64, 32><<<(n + 63) / 64, 256, 0, stream>>>(x, W1, bufA, n);
    gather64_fuse_kernel<<<((size_t)n * 64 + 255) / 256, 256, 0, stream>>>(
        bufA, row_ptr, edges, dinv, b1, W2, bufB, n);
    gather32_final_kernel<<<((size_t)n * 64 + 255) / 256, 256, 0, stream>>>(
        bufB, row_ptr, edges, dinv, b2, aw, ab, out, n);
}

// Round 5
// 250.289 us; speedup vs baseline: 1.2869x; 1.0520x over previous
//
#include <hip/hip_runtime.h>
#include <math.h>

#define N_NODES 50000
#define SLICE_SZ 6250          // N_NODES / 8 XCDs

__device__ __forceinline__ void fma4(float4& a, float w, const float4& v) {
    a.x += w * v.x; a.y += w * v.y; a.z += w * v.z; a.w += w * v.w;
}

// ---------------- degree histogram + per-edge rank ----------------
// rank[i] = arrival order of edge i at its dst -> later fill needs NO atomics.
__global__ void count_kernel(const int* __restrict__ dst, int E,
                             int* __restrict__ counts, int* __restrict__ rank) {
    int i = blockIdx.x * blockDim.x + threadIdx.x;
    if (i < E) rank[i] = atomicAdd(&counts[dst[i]], 1);
}

// ---------------- block-level exclusive scan ----------------
__global__ void scan_block_kernel(const int* __restrict__ in, int n,
                                  int* __restrict__ outEx, int* __restrict__ blocksum) {
    __shared__ int s[256];
    int t = threadIdx.x, i = blockIdx.x * 256 + t;
    int v = (i < n) ? in[i] : 0;
    s[t] = v;
    __syncthreads();
    for (int off = 1; off < 256; off <<= 1) {
        int x = (t >= off) ? s[t - off] : 0;
        __syncthreads();
        s[t] += x;
        __syncthreads();
    }
    if (i < n) outEx[i] = s[t] - v;
    if (t == 255 && blocksum) blocksum[blockIdx.x] = s[255];
}

__global__ void finalize_kernel(const int* __restrict__ counts, const int* __restrict__ blocksum,
                                int n, int E, int* __restrict__ row_ptr,
                                float* __restrict__ dinv) {
    int i = blockIdx.x * blockDim.x + threadIdx.x;
    if (i < n) {
        row_ptr[i] += blocksum[i >> 8];
        dinv[i] = rsqrtf((float)(counts[i] + 1));   // +1 self-loop
        if (i == 0) row_ptr[n] = E;
    }
}

// ---------------- XCD-sliced, atomic-free CSR fill ----------------
// p = row_ptr[dst] + rank  (precomputed) -> pure scatter, no atomics.
// dst-sliced so each 64B line of edges[] is assembled inside one L2.
__global__ void fill2_kernel(const int* __restrict__ src, const int* __restrict__ dst,
                             const int* __restrict__ rank, int E,
                             const int* __restrict__ row_ptr, const float* __restrict__ dinv,
                             int2* __restrict__ edges) {
    const int slice = blockIdx.x & 7;
    const int chunk = blockIdx.x >> 3;
    const int CS = (((E + 255) >> 8) + 3) & ~3;      // chunk size, multiple of 4
    const int lo = chunk * CS;
    const int hi = min(E, lo + CS);
    const int slo = slice * SLICE_SZ, shi = slo + SLICE_SZ;
    if (lo >= E) return;
    const int quad_end = lo + ((hi - lo) & ~3);
    for (int i = lo + threadIdx.x * 4; i + 3 < quad_end + 4 && i + 3 < hi + 4 && i < quad_end; i += 1024) {
        int4 d4 = *(const int4*)&dst[i];
        #pragma unroll
        for (int k = 0; k < 4; ++k) {
            int d = (&d4.x)[k];
            if (d >= slo && d < shi) {
                int s = src[i + k];
                int p = row_ptr[d] + rank[i + k];
                edges[p] = make_int2(s, __float_as_int(dinv[s] * dinv[d]));
            }
        }
    }
    for (int i = quad_end + threadIdx.x; i < hi; i += 256) {   // scalar tail
        int d = dst[i];
        if (d >= slo && d < shi) {
            int s = src[i];
            int p = row_ptr[d] + rank[i];
            edges[p] = make_int2(s, __float_as_int(dinv[s] * dinv[d]));
        }
    }
}

// ---------------- fp32 GEMM: C[n,DOUT] = A[n,DIN] @ W[DIN,DOUT] ----------------
template<int DIN, int DOUT, int BM, int KC>
__global__ __launch_bounds__(256, 2) void gemm_kernel(const float* __restrict__ A,
                                                      const float* __restrict__ W,
                                                      float* __restrict__ C, int n) {
    constexpr int NCG = DOUT / 4;
    constexpr int NRG = BM / 4;
    static_assert(NCG * NRG == 256, "thread mapping");
    constexpr int KG = KC / 4;
    constexpr int RSTEP = 256 / KG;
    __shared__ __align__(16) float ws[DIN * DOUT];
    __shared__ __align__(16) float xs[KC][BM + 4];
    const int t = threadIdx.x;
    for (int i = 4 * t; i < DIN * DOUT; i += 1024)
        *(float4*)&ws[i] = *(const float4*)&W[i];
    const int rowbase = blockIdx.x * BM;
    const int r0 = (t / NCG) * 4;
    const int c0 = (t % NCG) * 4;
    const int lk = (t % KG) * 4;
    const int lr = t / KG;
    float acc[4][4] = {};
    for (int kc = 0; kc < DIN; kc += KC) {
        __syncthreads();
        #pragma unroll
        for (int r = lr; r < BM; r += RSTEP) {
            int row = rowbase + r;
            if (row >= n) row = n - 1;
            float4 v = *(const float4*)&A[(size_t)row * DIN + kc + lk];
            xs[lk + 0][r] = v.x; xs[lk + 1][r] = v.y;
            xs[lk + 2][r] = v.z; xs[lk + 3][r] = v.w;
        }
        __syncthreads();
        #pragma unroll 8
        for (int k = 0; k < KC; ++k) {
            float ar[4], wr[4];
            *(float4*)ar = *(const float4*)&xs[k][r0];
            *(float4*)wr = *(const float4*)&ws[(kc + k) * DOUT + c0];
            #pragma unroll
            for (int i = 0; i < 4; ++i)
                #pragma unroll
                for (int j = 0; j < 4; ++j)
                    acc[i][j] += ar[i] * wr[j];
        }
    }
    #pragma unroll
    for (int i = 0; i < 4; ++i) {
        int row = rowbase + r0 + i;
        if (row < n) {
            float4 v = make_float4(acc[i][0], acc[i][1], acc[i][2], acc[i][3]);
            *(float4*)&C[(size_t)row * DOUT + c0] = v;
        }
    }
}

// ---------------- layer-1 gather (vectorized) + fused GEMM2 ----------------
// Wave per node. Lanes = 16 feature-groups (float4) x 4 edge-ways.
// Per edge: 16 lanes issue one dwordx4 gather each (vs 64 scalar) -> ~3x less VALU.
// Epilogue: y = h @ W2 via per-lane 4x8 partials from rotated+padded LDS W2
// (rot(j)=((j&7)<<2)|(j>>3), row pad 33 -> <=2-way bank conflicts), shfl-reduce.
__global__ __launch_bounds__(256) void gather64_fuse_kernel(
        const float* __restrict__ XW, const int* __restrict__ row_ptr,
        const int2* __restrict__ edges, const float* __restrict__ dinv,
        const float* __restrict__ b1, const float* __restrict__ W2,
        float* __restrict__ out, int n) {
    __shared__ float ws2R[64 * 33];
    const int t = threadIdx.x;
    for (int i = t; i < 64 * 32; i += 256) {
        int f = i >> 5, j = i & 31;
        ws2R[f * 33 + (((j & 7) << 2) | (j >> 3))] = W2[i];
    }
    __syncthreads();
    const int node = blockIdx.x * 4 + (t >> 6);
    if (node >= n) return;
    const int lane = t & 63;
    const int fg = lane & 15, way = lane >> 4;
    const float4* __restrict__ XW4 = (const float4*)XW;
    float4 acc = make_float4(0.f, 0.f, 0.f, 0.f);
    if (way == 0) {
        float dv = dinv[node];
        float4 v = XW4[(size_t)node * 16 + fg];
        float s2 = dv * dv;
        acc.x = s2 * v.x; acc.y = s2 * v.y; acc.z = s2 * v.z; acc.w = s2 * v.w;
    }
    int e = row_ptr[node] + way;
    const int end = row_ptr[node + 1];
    for (; e + 4 < end; e += 8) {
        int2 p0 = edges[e], p1 = edges[e + 4];
        float4 v0 = XW4[(size_t)p0.x * 16 + fg];
        float4 v1 = XW4[(size_t)p1.x * 16 + fg];
        fma4(acc, __int_as_float(p0.y), v0);
        fma4(acc, __int_as_float(p1.y), v1);
    }
    for (; e < end; e += 4) {
        int2 p = edges[e];
        float4 v = XW4[(size_t)p.x * 16 + fg];
        fma4(acc, __int_as_float(p.y), v);
    }
    // reduce across the 4 ways (lane bits 4,5)
    #pragma unroll
    for (int m = 16; m <= 32; m <<= 1) {
        acc.x += __shfl_xor(acc.x, m, 64);
        acc.y += __shfl_xor(acc.y, m, 64);
        acc.z += __shfl_xor(acc.z, m, 64);
        acc.w += __shfl_xor(acc.w, m, 64);
    }
    float4 b = ((const float4*)b1)[fg];
    float4 h;
    h.x = fmaxf(acc.x + b.x, 0.f);
    h.y = fmaxf(acc.y + b.y, 0.f);
    h.z = fmaxf(acc.z + b.z, 0.f);
    h.w = fmaxf(acc.w + b.w, 0.f);
    // fused GEMM2: lane computes partials for cols j = way*8 + s over its 4 features
    const int rbase = fg * 132;          // (4*fg)*33
    float py[8];
    #pragma unroll
    for (int s = 0; s < 8; ++s) {
        int idx = rbase + 4 * s + way;
        py[s] = h.x * ws2R[idx]
              + h.y * ws2R[idx + 33]
              + h.z * ws2R[idx + 66]
              + h.w * ws2R[idx + 99];
    }
    #pragma unroll
    for (int m = 1; m <= 8; m <<= 1) {
        #pragma unroll
        for (int s = 0; s < 8; ++s) py[s] += __shfl_xor(py[s], m, 64);
    }
    if (fg == 0) {
        float4* o = (float4*)&out[(size_t)node * 32 + way * 8];
        o[0] = make_float4(py[0], py[1], py[2], py[3]);
        o[1] = make_float4(py[4], py[5], py[6], py[7]);
    }
}

// ---------------- layer-2 gather (vectorized) + attention epilogue ----------------
// Wave per node. Lanes = 8 feature-groups (float4 over 32 cols) x 8 edge-ways.
__global__ __launch_bounds__(256) void gather32_final_kernel(
        const float* __restrict__ XW, const int* __restrict__ row_ptr,
        const int2* __restrict__ edges, const float* __restrict__ dinv,
        const float* __restrict__ b2, const float* __restrict__ aw,
        const float* __restrict__ ab, float* __restrict__ out, int n) {
    const int t = threadIdx.x;
    const int node = blockIdx.x * 4 + (t >> 6);
    if (node >= n) return;
    const int lane = t & 63;
    const int fg = lane & 7, way = lane >> 3;
    const float4* __restrict__ XW4 = (const float4*)XW;
    float4 acc = make_float4(0.f, 0.f, 0.f, 0.f);
    if (way == 0) {
        float dv = dinv[node];
        float4 v = XW4[(size_t)node * 8 + fg];
        float s2 = dv * dv;
        acc.x = s2 * v.x; acc.y = s2 * v.y; acc.z = s2 * v.z; acc.w = s2 * v.w;
    }
    int e = row_ptr[node] + way;
    const int end = row_ptr[node + 1];
    for (; e + 8 < end; e += 16) {
        int2 p0 = edges[e], p1 = edges[e + 8];
        float4 v0 = XW4[(size_t)p0.x * 8 + fg];
        float4 v1 = XW4[(size_t)p1.x * 8 + fg];
        fma4(acc, __int_as_float(p0.y), v0);
        fma4(acc, __int_as_float(p1.y), v1);
    }
    for (; e < end; e += 8) {
        int2 p = edges[e];
        fma4(acc, __int_as_float(p.y), XW4[(size_t)p.x * 8 + fg]);
    }
    // reduce across the 8 ways (lane bits 3,4,5)
    #pragma unroll
    for (int m = 8; m <= 32; m <<= 1) {
        acc.x += __shfl_xor(acc.x, m, 64);
        acc.y += __shfl_xor(acc.y, m, 64);
        acc.z += __shfl_xor(acc.z, m, 64);
        acc.w += __shfl_xor(acc.w, m, 64);
    }
    float4 b = ((const float4*)b2)[fg];
    float4 h;
    h.x = fmaxf(acc.x + b.x, 0.f);
    h.y = fmaxf(acc.y + b.y, 0.f);
    h.z = fmaxf(acc.z + b.z, 0.f);
    h.w = fmaxf(acc.w + b.w, 0.f);
    float4 a4 = ((const float4*)aw)[fg];
    float sca = h.x * a4.x + h.y * a4.y + h.z * a4.z + h.w * a4.w;
    sca += __shfl_xor(sca, 1, 64);
    sca += __shfl_xor(sca, 2, 64);
    sca += __shfl_xor(sca, 4, 64);
    float attn = 1.f / (1.f + __expf(-(sca + ab[0])));
    if (way == 0) {
        float4 r = make_float4(h.x * attn, h.y * attn, h.z * attn, h.w * attn);
        ((float4*)&out[(size_t)node * 32])[fg] = r;
    }
}

extern "C" void kernel_launch(void* const* d_in, const int* in_sizes, int n_in,
                              void* d_out, int out_size, void* d_ws, size_t ws_size,
                              hipStream_t stream) {
    const float* x  = (const float*)d_in[0];
    const int*   ei = (const int*)d_in[1];
    const float* W1 = (const float*)d_in[2];
    const float* b1 = (const float*)d_in[3];
    const float* W2 = (const float*)d_in[4];
    const float* b2 = (const float*)d_in[5];
    const float* aw = (const float*)d_in[6];
    const float* ab = (const float*)d_in[7];
    float* out = (float*)d_out;

    const int n = N_NODES;
    const int E = in_sizes[1] / 2;
    const int* src = ei;
    const int* dst = ei + E;

    char* w = (char*)d_ws;
    auto alloc = [&](size_t bytes) { char* p = w; w += (bytes + 255) & ~(size_t)255; return p; };
    int*   counts   = (int*)  alloc((size_t)n * 4);
    int*   row_ptr  = (int*)  alloc((size_t)(n + 1) * 4);
    int*   rank     = (int*)  alloc((size_t)E * 4);
    int*   blocksum = (int*)  alloc(1024);
    float* dinv     = (float*)alloc((size_t)n * 4);
    int2*  edges    = (int2*) alloc((size_t)E * 8);
    float* bufA     = (float*)alloc((size_t)n * 64 * 4);   // XW1
    float* bufB     = (float*)alloc((size_t)n * 32 * 4);   // XW2 (= h1 @ W2)

    const int nb = (n + 255) / 256;

    hipMemsetAsync(counts, 0, (size_t)n * 4, stream);
    count_kernel<<<(E + 255) / 256, 256, 0, stream>>>(dst, E, counts, rank);
    scan_block_kernel<<<nb, 256, 0, stream>>>(counts, n, row_ptr, blocksum);
    scan_block_kernel<<<1, 256, 0, stream>>>(blocksum, nb, blocksum, nullptr);
    finalize_kernel<<<nb, 256, 0, stream>>>(counts, blocksum, n, E, row_ptr, dinv);
    fill2_kernel<<<256 * 8, 256, 0, stream>>>(src, dst, rank, E, row_ptr, dinv, edges);

    gemm_kernel<128, 64, 64, 32><<<(n + 63) / 64, 256, 0, stream>>>(x, W1, bufA, n);
    gather64_fuse_kernel<<<(n + 3) / 4, 256, 0, stream>>>(
        bufA, row_ptr, edges, dinv, b1, W2, bufB, n);
    gather32_final_kernel<<<(n + 3) / 4, 256, 0, stream>>>(
        bufB, row_ptr, edges, dinv, b2, aw, ab, out, n);
}